// Round 4
// baseline (1375.714 us; speedup 1.0000x reference)
//
#include <hip/hip_runtime.h>
#include <math.h>

// ---------------------------------------------------------------------------
// B=2048, N=15, C=1024, H=16, HS=64; M = B*N = 30720 rows.
// All GEMMs: A[M][K] bf16 x Bt[N][K] bf16 (weights pre-transposed) -> C.
//
// gemm256: 256x256 block tile, BK=64, 512 threads = 8 waves (2M x 4N),
// per-wave 128x64 output (acc[8][4] of 16x16 frags). 128 KiB LDS double
// buffer. 4 phases per K-tile: {1 half-tile global_load_lds issue ||
// ds_read_b128 subtile || 16 MFMA in setprio}. Barriers after ph1/ph2/ph3;
// ONE counted s_waitcnt vmcnt(4) per K-tile (never 0 mid-loop). LDS
// XOR-swizzle (slot ^= row&7) via pre-swizzled GLOBAL source + swizzled
// ds_read (linear gload_lds dest) -> near-zero bank conflicts.
//
// NEW (R4): full-3D XCD-locality block remap. HW dispatch round-robins the
// z-major linear block id over 8 XCDs (per-XCD L2 = 4 MiB, not coherent).
// We recover gid, xcd = gid&7, and hand each XCD a contiguous run of a
// column-group-serpentine work order: groups of GC columns; inside a group
// rows advance with the GC columns innermost:
//   w = ((z*ncg + cg)*gy + by)*GC + ci,  bx = cg*GC+ci,  ncg = gx/GC.
// Per-XCD B working set = GC panels (<=2 MiB) -> L2-resident; A row panels
// stream through a short window. qkv GC=3 (each XCD = one (stream, 3-col)
// slab), proj/fc2 GC=4, fc1 GC=2. Replaces the z-blind m204 swizzle that
// gave each XCD ~20 MiB of operand working set (L2 thrash -> L3/HBM-feed
// bound at ~6.6k cy/K-tile vs ~1.2k at L2 speed).
//
// MFMA verified layouts:
//   A frag : lane holds A[m=lane&15][k=(lane>>4)*8+j], j=0..7
//   B frag : lane holds B[k=(lane>>4)*8+j][n=lane&15]  (== Bt[n][k] rows)
//   D      : lane reg r holds D[row=(lane>>4)*4+r][col=lane&15]
// Epilogue: acc -> per-wave LDS staging (16x68 f32) -> coalesced
// float4/ushort4 I/O. Row guard (Mtot) for qkv chunk tails.
//
// ws-ADAPTIVE: qkv processed in CH chunks of 30720/CH rows
// (CH in {1,2,4,8,16}; chunk multiple of 1920 = lcm(128,15)).
// peak ws = 205,520,896 + 754,974,720/CH bytes.
// ---------------------------------------------------------------------------

typedef __attribute__((ext_vector_type(8))) short short8;
typedef __attribute__((ext_vector_type(4))) float fx4;

#define MROWS 30720

// global(AS1) -> LDS(AS3) 16-byte async copy; LDS dest = wave-uniform base + lane*16
#define GLL16(g, l)                                                         \
    __builtin_amdgcn_global_load_lds(                                       \
        (const __attribute__((address_space(1))) unsigned int*)(g),         \
        (__attribute__((address_space(3))) unsigned int*)(l), 16, 0, 0)

__device__ inline unsigned short f2bf(float f) {
    unsigned int u = __float_as_uint(f);
    unsigned int r = (u + 0x7fffu + ((u >> 16) & 1u)) >> 16;
    return (unsigned short)r;
}
__device__ inline float bf2f(unsigned short s) {
    return __uint_as_float(((unsigned int)s) << 16);
}

// ---------------- weight transpose + bf16 cast:  W[K][N] -> Wt[N][K] --------
__global__ __launch_bounds__(256) void transpose_w(const float* __restrict__ W,
                                                   unsigned short* __restrict__ Wt,
                                                   int K, int N) {
    __shared__ float tile[32][33];
    int bn = blockIdx.x * 32;
    int bk = blockIdx.y * 32;
    int tx = threadIdx.x & 31, ty = threadIdx.x >> 5;   // 32 x 8
    #pragma unroll
    for (int i = ty; i < 32; i += 8)
        tile[i][tx] = W[(size_t)(bk + i) * N + bn + tx];
    __syncthreads();
    #pragma unroll
    for (int i = ty; i < 32; i += 8)
        Wt[(size_t)(bn + i) * K + bk + tx] = f2bf(tile[tx][i]);
}

// ---------------- LayerNorm over C=1024, fp32 in -> bf16 out ---------------
__global__ __launch_bounds__(256) void ln_dual(const float* __restrict__ xa,
                                               const float* __restrict__ ga,
                                               const float* __restrict__ bba,
                                               unsigned short* __restrict__ oa,
                                               const float* __restrict__ xb,
                                               const float* __restrict__ gb,
                                               const float* __restrict__ bbb,
                                               unsigned short* __restrict__ ob) {
    const float* x = blockIdx.y ? xb : xa;
    const float* g = blockIdx.y ? gb : ga;
    const float* bv = blockIdx.y ? bbb : bba;
    unsigned short* out = blockIdx.y ? ob : oa;

    int row = blockIdx.x;
    int t = threadIdx.x;
    const float4* xp = (const float4*)(x + (size_t)row * 1024);
    float4 v = xp[t];
    float s  = v.x + v.y + v.z + v.w;
    float ss = v.x * v.x + v.y * v.y + v.z * v.z + v.w * v.w;
    #pragma unroll
    for (int o = 32; o > 0; o >>= 1) { s += __shfl_down(s, o); ss += __shfl_down(ss, o); }
    __shared__ float ps[4], pss[4], stat[2];
    int wv = t >> 6, ln = t & 63;
    if (ln == 0) { ps[wv] = s; pss[wv] = ss; }
    __syncthreads();
    if (t == 0) {
        float S = ps[0] + ps[1] + ps[2] + ps[3];
        float SS = pss[0] + pss[1] + pss[2] + pss[3];
        float m = S * (1.0f / 1024.0f);
        float var = SS * (1.0f / 1024.0f) - m * m;
        stat[0] = m; stat[1] = rsqrtf(var + 1e-5f);
    }
    __syncthreads();
    float m = stat[0], r = stat[1];
    float4 gg = ((const float4*)g)[t];
    float4 bb = ((const float4*)bv)[t];
    ushort4 o;
    o.x = f2bf((v.x - m) * r * gg.x + bb.x);
    o.y = f2bf((v.y - m) * r * gg.y + bb.y);
    o.z = f2bf((v.z - m) * r * gg.z + bb.z);
    o.w = f2bf((v.w - m) * r * gg.w + bb.w);
    ((ushort4*)(out + (size_t)row * 1024))[t] = o;
}

// ---------------- 256^2 8-phase-style bf16 MFMA GEMM, fused epilogues ------
// EPI 0: outB = bf16(acc); decoded z==1 selects (A2,Bt2,outB2)
// EPI 1: outF = acc + bias[col] + resid[row][col]        (fp32 out)
// EPI 2: outB = bf16(gelu_exact(acc + bias[col]))
template <int EPI, int K>
__global__ __launch_bounds__(512, 2) void gemm256(const unsigned short* __restrict__ A,
                                                  const unsigned short* __restrict__ Bt,
                                                  const unsigned short* __restrict__ A2,
                                                  const unsigned short* __restrict__ Bt2,
                                                  const float* __restrict__ bias,
                                                  const float* __restrict__ resid,
                                                  float* __restrict__ outF,
                                                  unsigned short* __restrict__ outB,
                                                  unsigned short* __restrict__ outB2,
                                                  int N, int Mtot, int GC) {
    // 2 bufs x {A0@0, A1@8192, B0@16384, B1@24576} ushorts (16 KiB each half)
    __shared__ unsigned short sm[65536];   // 128 KiB

    const int tid = threadIdx.x;
    const int wid = tid >> 6, lane = tid & 63;
    const int rowf = lane & 15, quad = lane >> 4;
    const int wrow = wid >> 2, wcol = wid & 3;

    // ---- full-3D XCD-locality remap (see header) ----
    int bx, by;
    {
        const int gx = gridDim.x, gy = gridDim.y;
        int gid = ((int)blockIdx.z * gy + (int)blockIdx.y) * gx + (int)blockIdx.x;
        int nwg = gx * gy * (int)gridDim.z;
        int xcd = gid & 7, pos = gid >> 3;
        int q = nwg >> 3, r = nwg & 7;
        int w = (xcd < r ? xcd * (q + 1) : r * (q + 1) + (xcd - r) * q) + pos;
        int ci = w % GC;
        int t1 = w / GC;
        by = t1 % gy;
        int t2 = t1 / gy;
        int ncg = gx / GC;
        int cg = t2 % ncg;
        int z  = t2 / ncg;
        bx = cg * GC + ci;
        if (EPI == 0 && z) { A = A2; Bt = Bt2; outB = outB2; }
    }
    const int m0 = by * 256, n0 = bx * 256;

    // ---- staging source pointers (pre-swizzled global column) ----
    // half-tile = [128 rows][64 k] bf16 = 16 KiB; 2 gload issues (8 KiB each).
    // thread t, issue i: row = i*64 + (t>>3); 16B-slot = (t&7) ^ (row&7).
    const int srw  = tid >> 3;
    const int scol = ((tid & 7) ^ (srw & 7)) << 3;     // bf16 elems
    const unsigned short* pA[2][2];
    const unsigned short* pB[2][2];
    #pragma unroll
    for (int h = 0; h < 2; h++)
        #pragma unroll
        for (int i = 0; i < 2; i++) {
            pA[h][i] = A  + (size_t)(m0 + h * 128 + i * 64 + srw) * K + scol;
            pB[h][i] = Bt + (size_t)(n0 + h * 128 + i * 64 + srw) * K + scol;
        }

    // ds_read lane offsets (ushorts), slot ^= rowf&7 swizzle
    const int axk0 = rowf * 64 + ((quad ^ (rowf & 7)) << 3);
    const int axk1 = rowf * 64 + (((4 + quad) ^ (rowf & 7)) << 3);

    fx4 acc[8][4] = {};
    short8 a[4][2], b[4][2];
    const int NT = K / 64;

#define STG_A(H, D)                                                         \
    do {                                                                    \
        GLL16(pA[H][0], sm + ((D) << 15) + (H) * 8192 + wid * 512);         \
        GLL16(pA[H][1], sm + ((D) << 15) + (H) * 8192 + 4096 + wid * 512);  \
        pA[H][0] += 64; pA[H][1] += 64;                                     \
    } while (0)
#define STG_B(H, D)                                                         \
    do {                                                                    \
        GLL16(pB[H][0], sm + ((D) << 15) + 16384 + (H) * 8192 + wid * 512); \
        GLL16(pB[H][1], sm + ((D) << 15) + 16384 + (H) * 8192 + 4096 + wid * 512); \
        pB[H][0] += 64; pB[H][1] += 64;                                     \
    } while (0)
#define LDA4(BUFO, MS)                                                      \
    do {                                                                    \
        const unsigned short* _p = sm + (BUFO) + wrow * 8192 + (MS) * 4096; \
        _Pragma("unroll") for (int mi = 0; mi < 4; mi++) {                  \
            a[mi][0] = *(const short8*)(_p + mi * 1024 + axk0);             \
            a[mi][1] = *(const short8*)(_p + mi * 1024 + axk1);             \
        }                                                                   \
    } while (0)
#define LDB2(BUFO, PR)                                                      \
    do {                                                                    \
        const unsigned short* _p = sm + (BUFO) + 16384 + (wcol >> 1) * 8192 \
                                   + (wcol & 1) * 4096 + (PR) * 2048;       \
        _Pragma("unroll") for (int ni = 0; ni < 2; ni++) {                  \
            b[(PR) * 2 + ni][0] = *(const short8*)(_p + ni * 1024 + axk0);  \
            b[(PR) * 2 + ni][1] = *(const short8*)(_p + ni * 1024 + axk1);  \
        }                                                                   \
    } while (0)
#define MM16(MS, PR)                                                        \
    do {                                                                    \
        __builtin_amdgcn_s_setprio(1);                                      \
        _Pragma("unroll") for (int mi = 0; mi < 4; mi++)                    \
        _Pragma("unroll") for (int ni = 0; ni < 2; ni++) {                  \
            fx4 _c = acc[(MS) * 4 + mi][(PR) * 2 + ni];                     \
            _c = __builtin_amdgcn_mfma_f32_16x16x32_bf16(a[mi][0], b[(PR) * 2 + ni][0], _c, 0, 0, 0); \
            _c = __builtin_amdgcn_mfma_f32_16x16x32_bf16(a[mi][1], b[(PR) * 2 + ni][1], _c, 0, 0, 0); \
            acc[(MS) * 4 + mi][(PR) * 2 + ni] = _c;                         \
        }                                                                   \
        __builtin_amdgcn_s_setprio(0);                                      \
    } while (0)

    // ---- prologue: tile0 fully + tile1 {B0, A0} (queue-order matters) ----
    STG_A(0, 0); STG_A(1, 0); STG_B(0, 0); STG_B(1, 0);   // tile0 -> buf0
    STG_B(0, 1);                                          // tile1 B0 -> buf1
    STG_A(0, 1);                                          // tile1 A0 -> buf1
    asm volatile("s_waitcnt vmcnt(4)" ::: "memory");      // tile0 landed
    __builtin_amdgcn_s_barrier();

    #pragma unroll 2
    for (int t = 0; t < NT; ++t) {
        const int bufo = (t & 1) << 15;
        const bool s1 = (t + 1 < NT);
        const bool s2 = (t + 2 < NT);

        // ph0: stage A1(t+1); read A msel0 + B pair0; MFMA (m0-3 x n0-1)
        if (s1) STG_A(1, (t + 1) & 1);
        LDA4(bufo, 0);
        LDB2(bufo, 0);
        MM16(0, 0);
        // (no barrier: next stage targets a region free since last tile)

        // ph1: stage B1(t+1); read B pair1; MFMA (m0-3 x n2-3)
        if (s1) STG_B(1, (t + 1) & 1);
        LDB2(bufo, 1);
        MM16(0, 1);
        __builtin_amdgcn_sched_barrier(0);
        __builtin_amdgcn_s_barrier();      // frees B0/B1 of current buf

        // ph2: stage B0(t+2) into current buf; read A msel1; MFMA (m4-7 x n2-3)
        if (s2) STG_B(0, t & 1);
        LDA4(bufo, 1);
        MM16(1, 1);
        __builtin_amdgcn_sched_barrier(0);
        __builtin_amdgcn_s_barrier();      // frees A0/A1 of current buf

        // ph3: stage A0(t+2) into current buf; MFMA (m4-7 x n0-1); counted wait
        if (s2) STG_A(0, t & 1);
        MM16(1, 0);
        if (s1) {
            if (s2) asm volatile("s_waitcnt vmcnt(4)" ::: "memory"); // tile t+1 landed, 2 halves in flight
            else    asm volatile("s_waitcnt vmcnt(0)" ::: "memory"); // last prefetched tile
        }
        __builtin_amdgcn_sched_barrier(0);
        __builtin_amdgcn_s_barrier();      // validates tile t+1 for ph0 reads
    }
#undef STG_A
#undef STG_B
#undef LDA4
#undef LDB2
#undef MM16

    // ---- epilogue: per-wave LDS transpose -> coalesced vector I/O ----
    // wave-private 16x68 f32 staging in (dead) buf0 region.
    float* st = (float*)sm + wid * 1088;
    const int c4 = lane & 15;
    const int rquad = lane >> 4;
    const int colb = n0 + wcol * 64 + c4 * 4;
    float4 bb4 = {0.0f, 0.0f, 0.0f, 0.0f};
    if (EPI != 0) bb4 = *(const float4*)(bias + colb);

    #pragma unroll
    for (int mf = 0; mf < 8; mf++) {
        #pragma unroll
        for (int nf = 0; nf < 4; nf++)
            #pragma unroll
            for (int r = 0; r < 4; r++)
                st[(quad * 4 + r) * 68 + nf * 16 + rowf] = acc[mf][nf][r];
        // wave-local RAW on LDS: compiler inserts lgkmcnt; regions per-wave.
        #pragma unroll
        for (int rr = 0; rr < 4; rr++) {
            int lrow = rr * 4 + rquad;
            float4 v = *(const float4*)(st + lrow * 68 + c4 * 4);
            int grow = m0 + wrow * 128 + mf * 16 + lrow;
            if (grow < Mtot) {
                size_t off = (size_t)grow * N + colb;
                if (EPI == 1) {
                    float4 rr4 = *(const float4*)(resid + off);
                    v.x += bb4.x + rr4.x; v.y += bb4.y + rr4.y;
                    v.z += bb4.z + rr4.z; v.w += bb4.w + rr4.w;
                    *(float4*)(outF + off) = v;
                } else if (EPI == 2) {
                    float f0 = v.x + bb4.x, f1 = v.y + bb4.y;
                    float f2 = v.z + bb4.z, f3 = v.w + bb4.w;
                    f0 = 0.5f * f0 * (1.0f + erff(f0 * 0.70710678118654752f));
                    f1 = 0.5f * f1 * (1.0f + erff(f1 * 0.70710678118654752f));
                    f2 = 0.5f * f2 * (1.0f + erff(f2 * 0.70710678118654752f));
                    f3 = 0.5f * f3 * (1.0f + erff(f3 * 0.70710678118654752f));
                    ushort4 o;
                    o.x = f2bf(f0); o.y = f2bf(f1); o.z = f2bf(f2); o.w = f2bf(f3);
                    *(ushort4*)(outB + off) = o;
                } else {
                    ushort4 o;
                    o.x = f2bf(v.x); o.y = f2bf(v.y); o.z = f2bf(v.z); o.w = f2bf(v.w);
                    *(ushort4*)(outB + off) = o;
                }
            }
        }
    }
}

// ---------------- attention: one block per (chunk-local b, h) --------------
__global__ __launch_bounds__(256) void attn_kernel(const unsigned short* __restrict__ Jqkv,
                                                   const unsigned short* __restrict__ Iqkv,
                                                   const float* __restrict__ Wc,
                                                   unsigned short* __restrict__ xout) {
    int b = blockIdx.x >> 4;
    int h = blockIdx.x & 15;
    __shared__ float J[3][15][65];
    __shared__ float I[3][15][65];
    __shared__ float W[64][17];
    __shared__ float P[15][16];

    const unsigned short* Jb = Jqkv + (size_t)b * 15 * 3072 + h * 64;
    const unsigned short* Ib = Iqkv + (size_t)b * 15 * 3072 + h * 64;

    // vectorized 16B loads: 360 chunks of 8 bf16 per stream
    for (int idx = threadIdx.x; idx < 360; idx += 256) {
        int n = idx / 24, rem = idx % 24;
        int r = rem >> 3, d0 = (rem & 7) * 8;
        short8 vj = *(const short8*)(Jb + (size_t)n * 3072 + r * 1024 + d0);
        short8 vi = *(const short8*)(Ib + (size_t)n * 3072 + r * 1024 + d0);
        #pragma unroll
        for (int e = 0; e < 8; e++) {
            J[r][n][d0 + e] = bf2f((unsigned short)vj[e]);
            I[r][n][d0 + e] = bf2f((unsigned short)vi[e]);
        }
    }
    for (int idx = threadIdx.x; idx < 64 * 15; idx += 256)
        W[idx / 15][idx % 15] = Wc[idx];
    __syncthreads();

    for (int idx = threadIdx.x; idx < 225; idx += 256) {
        int q = idx / 15, kk = idx % 15;
        float s = 0.0f;
        #pragma unroll 8
        for (int d = 0; d < 64; d++)
            s += J[0][q][d] * J[1][kk][d] + I[0][q][d] * I[1][kk][d] + I[2][q][d] * W[d][kk];
        P[q][kk] = s * 0.125f;
    }
    __syncthreads();

    if (threadIdx.x < 15) {
        int q = threadIdx.x;
        float mx = -1e30f;
        #pragma unroll
        for (int kk = 0; kk < 15; kk++) mx = fmaxf(mx, P[q][kk]);
        float e[15], sum = 0.0f;
        #pragma unroll
        for (int kk = 0; kk < 15; kk++) { e[kk] = __expf(P[q][kk] - mx); sum += e[kk]; }
        float inv = 1.0f / sum;
        #pragma unroll
        for (int kk = 0; kk < 15; kk++) P[q][kk] = e[kk] * inv;
    }
    __syncthreads();

    // vectorized ushort4 output: 240 chunks of 4
    for (int idx = threadIdx.x; idx < 240; idx += 256) {
        int q = idx >> 4, d0 = (idx & 15) * 4;
        float o0 = 0.0f, o1 = 0.0f, o2 = 0.0f, o3 = 0.0f;
        #pragma unroll
        for (int kk = 0; kk < 15; kk++) {
            float p = P[q][kk];
            o0 += p * J[2][kk][d0 + 0];
            o1 += p * J[2][kk][d0 + 1];
            o2 += p * J[2][kk][d0 + 2];
            o3 += p * J[2][kk][d0 + 3];
        }
        ushort4 o;
        o.x = f2bf(o0); o.y = f2bf(o1); o.z = f2bf(o2); o.w = f2bf(o3);
        *(ushort4*)(xout + ((size_t)b * 15 + q) * 1024 + h * 64 + d0) = o;
    }
}

// ---------------------------------------------------------------------------
extern "C" void kernel_launch(void* const* d_in, const int* in_sizes, int n_in,
                              void* d_out, int out_size, void* d_ws, size_t ws_size,
                              hipStream_t stream) {
    const float* joint_feature    = (const float*)d_in[0];
    const float* relation_feature = (const float*)d_in[1];
    const float* W_Jqkv  = (const float*)d_in[2];
    const float* W_Iqk   = (const float*)d_in[3];
    const float* W_Iconv = (const float*)d_in[4];
    const float* W_proj  = (const float*)d_in[5];
    const float* b_proj  = (const float*)d_in[6];
    const float* g1  = (const float*)d_in[7];
    const float* be1 = (const float*)d_in[8];
    const float* g2  = (const float*)d_in[9];
    const float* be2 = (const float*)d_in[10];
    const float* gj  = (const float*)d_in[11];
    const float* bj  = (const float*)d_in[12];
    const float* W_fc1 = (const float*)d_in[13];
    const float* b_fc1 = (const float*)d_in[14];
    const float* W_fc2 = (const float*)d_in[15];
    const float* b_fc2 = (const float*)d_in[16];

    char* ws = (char*)d_ws;
    // -------- fixed region [0, 205,520,896) --------
    unsigned short* WtJ  = (unsigned short*)(ws + 0);          //  [3072][1024]
    unsigned short* WtI  = (unsigned short*)(ws + 6291456);    //  [3072][1024]
    unsigned short* WtP  = (unsigned short*)(ws + 12582912);   //  [1024][1024]
    unsigned short* WtF1 = (unsigned short*)(ws + 14680064);   //  [512][1024]
    unsigned short* WtF2 = (unsigned short*)(ws + 15728640);   //  [1024][512]
    unsigned short* xj   = (unsigned short*)(ws + 16777216);   //  [M][1024] bf16
    unsigned short* xi   = (unsigned short*)(ws + 79691776);   //  [M][1024] bf16
    unsigned short* xattn = (unsigned short*)(ws + 142606336); //  [M][1024] bf16
    // -------- reused regions --------
    float*          joint = (float*)(ws + 16777216);           // fp32 [M][1024] over dead xj+xi
    unsigned short* yln   = xattn;                             // xattn dead after proj
    unsigned short* h1    = (unsigned short*)(ws + 205520896); // bf16 [M][512]
    // -------- chunked qkv region --------
    int CH = 16;
    {
        const int opts[5] = {1, 2, 4, 8, 16};
        for (int i = 0; i < 5; i++) {
            size_t need = 205520896ull + 754974720ull / (size_t)opts[i];
            if (need <= ws_size) { CH = opts[i]; break; }
        }
    }
    const int Mc = MROWS / CH;                      // multiple of 1920
    const size_t chunkBytes = 754974720ull / (size_t)CH / 2ull;
    unsigned short* Jqkv_c = (unsigned short*)(ws + 205520896);
    unsigned short* Iqkv_c = (unsigned short*)(ws + 205520896 + chunkBytes);

    dim3 blk(256);
    dim3 blk5(512);

    // 1) transpose + bf16-cast weights
    transpose_w<<<dim3(96, 32), blk, 0, stream>>>(W_Jqkv, WtJ, 1024, 3072);
    transpose_w<<<dim3(96, 32), blk, 0, stream>>>(W_Iqk,  WtI, 1024, 3072);
    transpose_w<<<dim3(32, 32), blk, 0, stream>>>(W_proj, WtP, 1024, 1024);
    transpose_w<<<dim3(16, 32), blk, 0, stream>>>(W_fc1, WtF1, 1024, 512);
    transpose_w<<<dim3(32, 16), blk, 0, stream>>>(W_fc2, WtF2, 512, 1024);

    // 2) LN both input streams -> bf16
    ln_dual<<<dim3(MROWS, 2), blk, 0, stream>>>(joint_feature, g1, be1, xj,
                                                relation_feature, g2, be2, xi);

    // 3+4) chunked: qkv GEMM (both streams via grid.z) then attention
    const int My = (Mc + 255) >> 8;
    for (int c = 0; c < CH; c++) {
        size_t ro = (size_t)c * Mc * 1024;
        gemm256<0, 1024><<<dim3(12, My, 2), blk5, 0, stream>>>(
            xj + ro, WtJ, xi + ro, WtI, nullptr, nullptr, nullptr, Jqkv_c, Iqkv_c, 3072, Mc, 3);
        attn_kernel<<<(Mc / 15) * 16, blk, 0, stream>>>(Jqkv_c, Iqkv_c, W_Iconv, xattn + ro);
    }

    // 5) proj + bias + residual(joint_feature) -> joint (fp32)
    gemm256<1, 1024><<<dim3(4, 120), blk5, 0, stream>>>(
        xattn, WtP, nullptr, nullptr, b_proj, joint_feature, joint, nullptr, nullptr, 1024, MROWS, 4);

    // 6) LN(joint) -> yln
    ln_dual<<<dim3(MROWS, 1), blk, 0, stream>>>(joint, gj, bj, yln,
                                                nullptr, nullptr, nullptr, nullptr);

    // 7) fc1 + bias + gelu -> h1 (bf16)
    gemm256<2, 1024><<<dim3(2, 120), blk5, 0, stream>>>(
        yln, WtF1, nullptr, nullptr, b_fc1, nullptr, nullptr, h1, nullptr, 512, MROWS, 2);

    // 8) fc2 + bias + residual(joint) -> d_out (fp32)
    gemm256<1, 512><<<dim3(4, 120), blk5, 0, stream>>>(
        h1, WtF2, nullptr, nullptr, b_fc2, joint, (float*)d_out, nullptr, nullptr, 1024, MROWS, 4);
}